// Round 7
// baseline (345.002 us; speedup 1.0000x reference)
//
#include <hip/hip_runtime.h>
#include <hip/hip_bf16.h>

// Problem constants (B=2, T=2048, C=2048, NH=16, L=128)
#define B_   2
#define T_   2048
#define C_   2048
#define NH_  16
#define L_   128
#define NKQ  2176   // L_ + NH_*L_
#define MTOK 4096   // B_*T_
#define SCALE2_ 0.12753785792696073f          // (1/sqrt(128)) * log2(e)

typedef short short8 __attribute__((ext_vector_type(8)));
typedef float f32x4  __attribute__((ext_vector_type(4)));
typedef float f32x16 __attribute__((ext_vector_type(16)));

// async global->LDS, 16B per lane; LDS base must be wave-uniform.
#define GLD16(gp, lp) __builtin_amdgcn_global_load_lds(                      \
    (const __attribute__((address_space(1))) void*)(gp),                     \
    (__attribute__((address_space(3))) void*)(lp), 16, 0, 0)

__device__ __forceinline__ unsigned short f2bf(float f) {
  union { float f; unsigned u; } x; x.f = f;
  unsigned r = x.u + 0x7fffu + ((x.u >> 16) & 1u);   // RNE
  return (unsigned short)(r >> 16);
}

// ---------------- merged prep: cvt + 3 weight transposes + bias concat ----------------
__global__ __launch_bounds__(256) void prep_all(
    const float* __restrict__ x, const float* __restrict__ W_lat,
    const float* __restrict__ W_d, const float* __restrict__ W_proj,
    const float* __restrict__ b_lat, const float* __restrict__ b_d,
    unsigned short* __restrict__ x_bf, unsigned short* __restrict__ BtCat,
    unsigned short* __restrict__ WprojT, float* __restrict__ biascat) {
  __shared__ float tile[32][33];
  int bid = blockIdx.x;
  const int tid = threadIdx.x;

  if (bid < 8192) {                       // x fp32 -> bf16, 4 elems/thread
    int i = bid * 1024 + tid * 4;
    float4 v = *(const float4*)(x + i);
    ushort4 o;
    o.x = f2bf(v.x); o.y = f2bf(v.y); o.z = f2bf(v.z); o.w = f2bf(v.w);
    *(ushort4*)(x_bf + i) = o;
    return;
  }
  bid -= 8192;

  const float* W; unsigned short* Wt; int K, N; float mul; int nbx;
  if (bid < 256) {                        // W_lat [C][L] -> BtCat[0:L][C]
    W = W_lat; Wt = BtCat; K = C_; N = L_; mul = 1.f; nbx = 4;
  } else if (bid < 256 + 4096) {          // W_d [C][2048] -> BtCat[L:][C], fold scale*log2e
    bid -= 256;
    W = W_d; Wt = BtCat + (size_t)L_ * C_; K = C_; N = NH_ * L_; mul = SCALE2_; nbx = 64;
  } else if (bid < 256 + 8192) {          // W_proj [2048][C] -> WprojT[C][2048]
    bid -= 256 + 4096;
    W = W_proj; Wt = WprojT; K = NH_ * L_; N = C_; mul = 1.f; nbx = 64;
  } else {                                // bias concat [b_lat | scale*log2e*b_d]
    int i = (bid - (256 + 8192)) * 256 + tid;
    if (i < L_) biascat[i] = b_lat[i];
    else if (i < NKQ) biascat[i] = b_d[i - L_] * SCALE2_;
    return;
  }

  const int bx = (bid % nbx) * 32, by = (bid / nbx) * 32;
  const int tx = tid & 31, ty = tid >> 5;
  #pragma unroll
  for (int i2 = 0; i2 < 4; i2++)
    tile[ty + i2 * 8][tx] = W[(size_t)(by + ty + i2 * 8) * N + bx + tx];
  __syncthreads();
  #pragma unroll
  for (int i2 = 0; i2 < 4; i2++)
    Wt[(size_t)(bx + ty + i2 * 8) * K + by + tx] = f2bf(tile[tx][ty + i2 * 8] * mul);
}

// ---------------- bf16 MFMA GEMM:  C = A @ Bt^T + bias ----------------
// R6 (measured ~64-70us each): double-buffered LDS staging, 128x128 tile, BK=32.
// R9: GEMM1 additionally scatters the latent slab (cols 0..127) transposed into
// KlT[b][l][t] in the epilogue -> transpose_lat kernel eliminated.
__global__ __launch_bounds__(256) void gemm_bt_bias(
    const unsigned short* __restrict__ A,   // [M][K] bf16
    const unsigned short* __restrict__ Bt,  // [N][K] bf16
    const float* __restrict__ bias,         // [N]
    unsigned short* __restrict__ Cb,        // bf16 out (or null)
    float* __restrict__ Cf,                 // fp32 out (or null)
    unsigned short* __restrict__ KlTout,    // [B][L][T] transposed latent (or null)
    int M, int N, int K) {
  __shared__ __align__(16) unsigned short As[2][128 * 32];  // dbuf, BK=32
  __shared__ __align__(16) unsigned short Bs[2][128 * 32];
  const int tid  = threadIdx.x;
  const int wave = tid >> 6, lane = tid & 63;
  const int lcol = lane & 15, quad = lane >> 4;
  const int m0 = blockIdx.x * 128, n0 = blockIdx.y * 128;
  const int wm = (wave >> 1) * 64, wn = (wave & 1) * 64;
  const int lrow = lane >> 2, lchunk = (lane & 3) * 8;
  const int rb = wave * 32;

  f32x4 acc[4][4];
  #pragma unroll
  for (int i = 0; i < 4; i++)
    #pragma unroll
    for (int j = 0; j < 4; j++) acc[i][j] = (f32x4){0.f, 0.f, 0.f, 0.f};

  const int nk = K >> 5;
  // prologue: stage k-tile 0 into buffer 0
  GLD16(&A [(size_t)(m0 + rb      + lrow) * K + lchunk], &As[0][ rb       * 32]);
  GLD16(&A [(size_t)(m0 + rb + 16 + lrow) * K + lchunk], &As[0][(rb + 16) * 32]);
  GLD16(&Bt[(size_t)(n0 + rb      + lrow) * K + lchunk], &Bs[0][ rb       * 32]);
  GLD16(&Bt[(size_t)(n0 + rb + 16 + lrow) * K + lchunk], &Bs[0][(rb + 16) * 32]);

  for (int kt = 0; kt < nk; ++kt) {
    const int cur = kt & 1;
    __syncthreads();  // drains stage(kt) [issued one compute-phase ago] + guards buf reuse

    if (kt + 1 < nk) {  // prefetch next k-tile into the other buffer
      const int kc = (kt + 1) << 5;
      GLD16(&A [(size_t)(m0 + rb      + lrow) * K + kc + lchunk], &As[cur ^ 1][ rb       * 32]);
      GLD16(&A [(size_t)(m0 + rb + 16 + lrow) * K + kc + lchunk], &As[cur ^ 1][(rb + 16) * 32]);
      GLD16(&Bt[(size_t)(n0 + rb      + lrow) * K + kc + lchunk], &Bs[cur ^ 1][ rb       * 32]);
      GLD16(&Bt[(size_t)(n0 + rb + 16 + lrow) * K + kc + lchunk], &Bs[cur ^ 1][(rb + 16) * 32]);
    }

    short8 af[4], bfr[4];
    #pragma unroll
    for (int i = 0; i < 4; i++)
      af[i] = *(const short8*)&As[cur][(wm + i * 16 + lcol) * 32 + quad * 8];
    #pragma unroll
    for (int j = 0; j < 4; j++)
      bfr[j] = *(const short8*)&Bs[cur][(wn + j * 16 + lcol) * 32 + quad * 8];
    #pragma unroll
    for (int i = 0; i < 4; i++)
      #pragma unroll
      for (int j = 0; j < 4; j++)
        acc[i][j] = __builtin_amdgcn_mfma_f32_16x16x32_bf16(af[i], bfr[j], acc[i][j], 0, 0, 0);
  }

  #pragma unroll
  for (int i = 0; i < 4; i++) {
    #pragma unroll
    for (int j = 0; j < 4; j++) {
      int col = n0 + wn + j * 16 + lcol;
      float bv = bias[col];
      #pragma unroll
      for (int r = 0; r < 4; r++) {
        int row = m0 + wm + i * 16 + quad * 4 + r;
        float v = acc[i][j][r] + bv;
        if (Cf) Cf[(size_t)row * N + col] = v;
        else {
          unsigned short hv = f2bf(v);
          Cb[(size_t)row * N + col] = hv;
          if (KlTout && n0 == 0)   // latent slab: also write transposed [b][l][t]
            KlTout[((size_t)(row >> 11) * L_ + col) * T_ + (row & 2047)] = hv;
        }
      }
    }
  }
}

// ---------------- fused causal MLA attention (R9: zero-staging, zero-barrier) ----------------
// R8 lesson: attn was EXACTLY 70.5us across two different compute bodies with
// identical bank-conflict counts -> the stage->barrier->drain cadence was the
// critical path, compute fully hidden. R9: drop ALL LDS staging and ALL loop
// barriers. kq-latent (1MB/b) + KlT (1MB) are L2-resident (HBM only 470GB/s);
// R8's swizzle algebra unswizzles to CONTIGUOUS 16B global chunks:
//   K-frag = kq[rowbase+s1+sb*32+l31][(2kc+hf)*8..+8]
//   V-frag = KlT[b*L+rowv][s1+(2kc+hf)*8..+8]
// so frags load directly as global b128. K-frags batched (16 loads) before the
// QK^T MFMA cluster; V-frags double-buffered across kc (first batch hidden
// under exp2). Waves run fully unsynchronized -> 8 waves/CU hide latency.
// Everything else (swapped QK^T 32x32x16, in-reg cvt_pk+permlane32_swap P,
// per-lane lsum, no-max softmax, heavy/light block pairing) as in R8 (passed).
__global__ __launch_bounds__(256, 2) void attn_mla(
    const unsigned short* __restrict__ kq,   // [B*T][NKQ]
    const unsigned short* __restrict__ KlT,  // [B][L][T]
    unsigned short* __restrict__ y) {        // [B*T][NH*L]
  __shared__ __align__(16) float ls[4][32];  // per-wave 1/lsum exchange

  const int tid  = threadIdx.x;
  const int wave = tid >> 6, lane = tid & 63;
  const int l31 = lane & 31, hf = lane >> 5;
  const int n    = blockIdx.x;
  const int slot = n >> 8, c = n & 255;
  const int hg   = c >> 5, qi = c & 31;
  const int b    = hg >> 2;
  const int h    = (hg & 3) * 4 + wave;
  const int qt32 = slot ? qi : (63 - qi);    // 32-row q-tile index
  const size_t rowbase = (size_t)b * T_;
  const int q0 = qt32 * 32;

  // Q as B-frags for swapped QK^T (n = q = lane&31, k = kc*16 + hf*8 + j)
  short8 qf[8];
  {
    const unsigned short* qp =
        kq + (rowbase + q0 + l31) * NKQ + L_ + h * L_ + hf * 8;
    #pragma unroll
    for (int kc = 0; kc < 8; kc++)
      qf[kc] = *(const short8*)(qp + kc * 16);
  }

  // per-lane base pointers
  const unsigned short* kp0 = kq + (rowbase + l31) * NKQ;        // K row l31
  const unsigned short* vb[4];
  #pragma unroll
  for (int nb = 0; nb < 4; nb++)
    vb[nb] = KlT + ((size_t)b * L_ + nb * 32 + l31) * T_;

  f32x16 acco[4];   // O[32q][128l]: 4 n-blocks of 32; rows = reg-form, col = l31
  #pragma unroll
  for (int nb = 0; nb < 4; nb++)
    #pragma unroll
    for (int r = 0; r < 16; r++) acco[nb][r] = 0.f;
  float lsum = 0.f;

  const int nt = (qt32 >> 1) + 1;

  for (int ts = 0; ts < nt; ts++) {
    const int s1 = ts * 64;

    // batch all 16 K-frag loads (independent; compiler counts vmcnt into MFMAs)
    short8 kf[8][2];
    #pragma unroll
    for (int kc = 0; kc < 8; kc++)
      #pragma unroll
      for (int sb = 0; sb < 2; sb++)
        kf[kc][sb] = *(const short8*)(kp0 + (size_t)(s1 + sb * 32) * NKQ +
                                      (2 * kc + hf) * 8);

    // S^T(64s x 32q) = K @ Q^T
    f32x16 accs[2];
    #pragma unroll
    for (int sb = 0; sb < 2; sb++)
      #pragma unroll
      for (int r = 0; r < 16; r++) accs[sb][r] = 0.f;
    __builtin_amdgcn_s_setprio(1);
    #pragma unroll
    for (int kc = 0; kc < 8; kc++)
      #pragma unroll
      for (int sb = 0; sb < 2; sb++)
        accs[sb] = __builtin_amdgcn_mfma_f32_32x32x16_bf16(kf[kc][sb], qf[kc], accs[sb], 0, 0, 0);
    __builtin_amdgcn_s_setprio(0);

    // prefetch V-frags for kc=0 (consumed after exp -> latency hidden)
    short8 vfp[2][4];
    #pragma unroll
    for (int nb = 0; nb < 4; nb++)
      vfp[0][nb] = *(const short8*)(vb[nb] + s1 + hf * 8);

    // mask + p = 2^s (log2e pre-folded into W_d)
    const bool diag = (ts == nt - 1);
    const int qg = (qt32 & 1) * 32 + l31;
    #pragma unroll
    for (int sb = 0; sb < 2; sb++)
      #pragma unroll
      for (int r = 0; r < 16; r++) {
        float v = accs[sb][r];
        int s64 = sb * 32 + (r & 3) + 8 * (r >> 2) + 4 * hf;
        if (diag && s64 > qg) v = -1e30f;
        accs[sb][r] = __builtin_amdgcn_exp2f(v);
      }

    // PV: per kc (s-chunk of 16): A-frag in regs (cvt_pk + permlane32_swap),
    // V-frags double-buffered (load kc+1 before computing kc).
    #pragma unroll
    for (int kc = 0; kc < 4; kc++) {
      if (kc < 3) {
        #pragma unroll
        for (int nb = 0; nb < 4; nb++)
          vfp[(kc + 1) & 1][nb] =
              *(const short8*)(vb[nb] + s1 + (2 * (kc + 1) + hf) * 8);
      }
      const int sb = kc >> 1;
      const int t0 = (kc & 1) * 2;          // packs t0 (regs 4t0..) and t0+1
      unsigned w00, w01, w10, w11;
      asm("v_cvt_pk_bf16_f32 %0, %1, %2" : "=v"(w00)
          : "v"(accs[sb][4 * t0 + 0]), "v"(accs[sb][4 * t0 + 1]));
      asm("v_cvt_pk_bf16_f32 %0, %1, %2" : "=v"(w01)
          : "v"(accs[sb][4 * t0 + 2]), "v"(accs[sb][4 * t0 + 3]));
      asm("v_cvt_pk_bf16_f32 %0, %1, %2" : "=v"(w10)
          : "v"(accs[sb][4 * t0 + 4]), "v"(accs[sb][4 * t0 + 5]));
      asm("v_cvt_pk_bf16_f32 %0, %1, %2" : "=v"(w11)
          : "v"(accs[sb][4 * t0 + 6]), "v"(accs[sb][4 * t0 + 7]));
      // VDST.hi <-> VSRC.lo: w00' = {half0 pack[t0]}, w10' = {half1 pack[t]}
      asm volatile("v_permlane32_swap_b32 %0, %1" : "+v"(w00), "+v"(w10));
      asm volatile("v_permlane32_swap_b32 %0, %1" : "+v"(w01), "+v"(w11));
      union { short8 s; unsigned u[4]; } F;
      F.u[0] = w00; F.u[1] = w01; F.u[2] = w10; F.u[3] = w11;
      // lsum from the exact bf16 values fed to the MFMA (own q = l31)
      #pragma unroll
      for (int w = 0; w < 4; w++) {
        lsum += __uint_as_float(F.u[w] << 16);
        lsum += __uint_as_float(F.u[w] & 0xffff0000u);
      }
      __builtin_amdgcn_s_setprio(1);
      #pragma unroll
      for (int nb = 0; nb < 4; nb++)
        acco[nb] = __builtin_amdgcn_mfma_f32_32x32x16_bf16(F.s, vfp[kc & 1][nb], acco[nb], 0, 0, 0);
      __builtin_amdgcn_s_setprio(0);
    }
  }

  // lsum: merge halves, invert, exchange across lanes (per-wave LDS slot)
  lsum += __shfl_xor(lsum, 32, 64);
  if (lane < 32) ls[wave][l31] = 1.f / lsum;
  __syncthreads();
  f32x4 rv[4];
  #pragma unroll
  for (int t = 0; t < 4; t++)
    rv[t] = *(const f32x4*)&ls[wave][8 * t + 4 * hf];

  // write y: q = q0 + (r&3)+8*(r>>2)+4*hf (rows), l = nb*32 + l31 (cols)
  #pragma unroll
  for (int nb = 0; nb < 4; nb++)
    #pragma unroll
    for (int r = 0; r < 16; r++) {
      int q = q0 + (r & 3) + 8 * (r >> 2) + 4 * hf;
      int l = nb * 32 + l31;
      y[(rowbase + q) * (NH_ * L_) + h * L_ + l] =
          f2bf(acco[nb][r] * rv[r >> 2][r & 3]);
    }
}

extern "C" void kernel_launch(void* const* d_in, const int* in_sizes, int n_in,
                              void* d_out, int out_size, void* d_ws, size_t ws_size,
                              hipStream_t stream) {
  const float* x      = (const float*)d_in[0];
  const float* W_lat  = (const float*)d_in[1];
  const float* b_lat  = (const float*)d_in[2];
  const float* W_d    = (const float*)d_in[3];
  const float* b_d    = (const float*)d_in[4];
  const float* W_proj = (const float*)d_in[5];
  const float* b_proj = (const float*)d_in[6];
  float* out = (float*)d_out;

  // workspace layout (bf16 buffers, 16B aligned)
  unsigned short* x_bf   = (unsigned short*)d_ws;                  // [4096][2048]
  unsigned short* BtCat  = x_bf   + (size_t)MTOK * C_;             // [2176][2048]
  unsigned short* WprojT = BtCat  + (size_t)NKQ * C_;              // [2048][2048]
  unsigned short* kqbuf  = WprojT + (size_t)C_ * (NH_ * L_);       // [4096][2176]
  unsigned short* ybuf   = kqbuf  + (size_t)MTOK * NKQ;            // [4096][2048]
  unsigned short* KlT    = ybuf   + (size_t)MTOK * (NH_ * L_);     // [2][128][2048]
  float*          biascat = (float*)(KlT + (size_t)B_ * L_ * T_);  // [2176]

  // 1. merged prep: x->bf16, weight transposes (scale folded), bias concat
  prep_all<<<16649, 256, 0, stream>>>(x, W_lat, W_d, W_proj, b_lat, b_d,
                                      x_bf, BtCat, WprojT, biascat);
  // 2. kq = x @ [W_lat | scale*log2e*W_d] + bias (bf16 out) + fused latent transpose
  gemm_bt_bias<<<dim3(MTOK / 128, NKQ / 128), 256, 0, stream>>>(
      x_bf, BtCat, biascat, kqbuf, nullptr, KlT, MTOK, NKQ, C_);
  // 3. causal MLA attention (512 balanced blocks, zero-staging zero-barrier)
  attn_mla<<<512, 256, 0, stream>>>(kqbuf, KlT, ybuf);
  // 4. out = y @ W_proj + b_proj (fp32 out)
  gemm_bt_bias<<<dim3(MTOK / 128, C_ / 128), 256, 0, stream>>>(
      ybuf, WprojT, b_proj, nullptr, out, nullptr, MTOK, C_, C_);
}

// Round 8
// 280.189 us; speedup vs baseline: 1.2313x; 1.2313x over previous
//
#include <hip/hip_runtime.h>
#include <hip/hip_bf16.h>

// Problem constants (B=2, T=2048, C=2048, NH=16, L=128)
#define B_   2
#define T_   2048
#define C_   2048
#define NH_  16
#define L_   128
#define NKQ  2176   // L_ + NH_*L_
#define MTOK 4096   // B_*T_
#define SCALE2_ 0.12753785792696073f          // (1/sqrt(128)) * log2(e)

typedef short short8 __attribute__((ext_vector_type(8)));
typedef float f32x4  __attribute__((ext_vector_type(4)));
typedef float f32x16 __attribute__((ext_vector_type(16)));

// async global->LDS, 16B per lane; LDS base must be wave-uniform.
#define GLD16(gp, lp) __builtin_amdgcn_global_load_lds(                      \
    (const __attribute__((address_space(1))) void*)(gp),                     \
    (__attribute__((address_space(3))) void*)(lp), 16, 0, 0)

__device__ __forceinline__ unsigned short f2bf(float f) {
  union { float f; unsigned u; } x; x.f = f;
  unsigned r = x.u + 0x7fffu + ((x.u >> 16) & 1u);   // RNE
  return (unsigned short)(r >> 16);
}

// ---------------- merged prep: cvt + 3 weight transposes + bias concat ----------------
__global__ __launch_bounds__(256) void prep_all(
    const float* __restrict__ x, const float* __restrict__ W_lat,
    const float* __restrict__ W_d, const float* __restrict__ W_proj,
    const float* __restrict__ b_lat, const float* __restrict__ b_d,
    unsigned short* __restrict__ x_bf, unsigned short* __restrict__ BtCat,
    unsigned short* __restrict__ WprojT, float* __restrict__ biascat) {
  __shared__ float tile[32][33];
  int bid = blockIdx.x;
  const int tid = threadIdx.x;

  if (bid < 8192) {                       // x fp32 -> bf16, 4 elems/thread
    int i = bid * 1024 + tid * 4;
    float4 v = *(const float4*)(x + i);
    ushort4 o;
    o.x = f2bf(v.x); o.y = f2bf(v.y); o.z = f2bf(v.z); o.w = f2bf(v.w);
    *(ushort4*)(x_bf + i) = o;
    return;
  }
  bid -= 8192;

  const float* W; unsigned short* Wt; int K, N; float mul; int nbx;
  if (bid < 256) {                        // W_lat [C][L] -> BtCat[0:L][C]
    W = W_lat; Wt = BtCat; K = C_; N = L_; mul = 1.f; nbx = 4;
  } else if (bid < 256 + 4096) {          // W_d [C][2048] -> BtCat[L:][C], fold scale*log2e
    bid -= 256;
    W = W_d; Wt = BtCat + (size_t)L_ * C_; K = C_; N = NH_ * L_; mul = SCALE2_; nbx = 64;
  } else if (bid < 256 + 8192) {          // W_proj [2048][C] -> WprojT[C][2048]
    bid -= 256 + 4096;
    W = W_proj; Wt = WprojT; K = NH_ * L_; N = C_; mul = 1.f; nbx = 64;
  } else {                                // bias concat [b_lat | scale*log2e*b_d]
    int i = (bid - (256 + 8192)) * 256 + tid;
    if (i < L_) biascat[i] = b_lat[i];
    else if (i < NKQ) biascat[i] = b_d[i - L_] * SCALE2_;
    return;
  }

  const int bx = (bid % nbx) * 32, by = (bid / nbx) * 32;
  const int tx = tid & 31, ty = tid >> 5;
  #pragma unroll
  for (int i2 = 0; i2 < 4; i2++)
    tile[ty + i2 * 8][tx] = W[(size_t)(by + ty + i2 * 8) * N + bx + tx];
  __syncthreads();
  #pragma unroll
  for (int i2 = 0; i2 < 4; i2++)
    Wt[(size_t)(bx + ty + i2 * 8) * K + by + tx] = f2bf(tile[tx][ty + i2 * 8] * mul);
}

// ---------------- bf16 MFMA GEMM:  C = A @ Bt^T + bias ----------------
// R6 (measured ~64-70us each): double-buffered LDS staging, 128x128 tile, BK=32.
// R10: (a) GEMM1 scatters the latent slab transposed into KlT (epilogue fusion,
// passed R7); (b) T1 XCD-aware block swizzle: lin = y*gridX + x (dispatch order),
// xcd = lin&7, each XCD gets a contiguous 4-tile m-chunk (2MB of A, fits 4MB
// per-XCD L2) reused across all n-groups -> A re-reads become L2 hits.
// Bijective: both grids are multiples of 8 (544, 512) and gridX=32 = 8*4.
__global__ __launch_bounds__(256) void gemm_bt_bias(
    const unsigned short* __restrict__ A,   // [M][K] bf16
    const unsigned short* __restrict__ Bt,  // [N][K] bf16
    const float* __restrict__ bias,         // [N]
    unsigned short* __restrict__ Cb,        // bf16 out (or null)
    float* __restrict__ Cf,                 // fp32 out (or null)
    unsigned short* __restrict__ KlTout,    // [B][L][T] transposed latent (or null)
    int M, int N, int K) {
  __shared__ __align__(16) unsigned short As[2][128 * 32];  // dbuf, BK=32
  __shared__ __align__(16) unsigned short Bs[2][128 * 32];
  const int tid  = threadIdx.x;
  const int wave = tid >> 6, lane = tid & 63;
  const int lcol = lane & 15, quad = lane >> 4;
  // XCD-aware swizzle (T1)
  const int lin = blockIdx.y * gridDim.x + blockIdx.x;
  const int xcd = lin & 7, idx = lin >> 3;
  const int mpx = gridDim.x >> 3;                 // m-tiles per XCD chunk (4)
  const int m0 = (xcd * mpx + idx % mpx) * 128;
  const int n0 = (idx / mpx) * 128;
  const int wm = (wave >> 1) * 64, wn = (wave & 1) * 64;
  const int lrow = lane >> 2, lchunk = (lane & 3) * 8;
  const int rb = wave * 32;

  f32x4 acc[4][4];
  #pragma unroll
  for (int i = 0; i < 4; i++)
    #pragma unroll
    for (int j = 0; j < 4; j++) acc[i][j] = (f32x4){0.f, 0.f, 0.f, 0.f};

  const int nk = K >> 5;
  // prologue: stage k-tile 0 into buffer 0
  GLD16(&A [(size_t)(m0 + rb      + lrow) * K + lchunk], &As[0][ rb       * 32]);
  GLD16(&A [(size_t)(m0 + rb + 16 + lrow) * K + lchunk], &As[0][(rb + 16) * 32]);
  GLD16(&Bt[(size_t)(n0 + rb      + lrow) * K + lchunk], &Bs[0][ rb       * 32]);
  GLD16(&Bt[(size_t)(n0 + rb + 16 + lrow) * K + lchunk], &Bs[0][(rb + 16) * 32]);

  for (int kt = 0; kt < nk; ++kt) {
    const int cur = kt & 1;
    __syncthreads();  // drains stage(kt) [issued one compute-phase ago] + guards buf reuse

    if (kt + 1 < nk) {  // prefetch next k-tile into the other buffer
      const int kc = (kt + 1) << 5;
      GLD16(&A [(size_t)(m0 + rb      + lrow) * K + kc + lchunk], &As[cur ^ 1][ rb       * 32]);
      GLD16(&A [(size_t)(m0 + rb + 16 + lrow) * K + kc + lchunk], &As[cur ^ 1][(rb + 16) * 32]);
      GLD16(&Bt[(size_t)(n0 + rb      + lrow) * K + kc + lchunk], &Bs[cur ^ 1][ rb       * 32]);
      GLD16(&Bt[(size_t)(n0 + rb + 16 + lrow) * K + kc + lchunk], &Bs[cur ^ 1][(rb + 16) * 32]);
    }

    short8 af[4], bfr[4];
    #pragma unroll
    for (int i = 0; i < 4; i++)
      af[i] = *(const short8*)&As[cur][(wm + i * 16 + lcol) * 32 + quad * 8];
    #pragma unroll
    for (int j = 0; j < 4; j++)
      bfr[j] = *(const short8*)&Bs[cur][(wn + j * 16 + lcol) * 32 + quad * 8];
    #pragma unroll
    for (int i = 0; i < 4; i++)
      #pragma unroll
      for (int j = 0; j < 4; j++)
        acc[i][j] = __builtin_amdgcn_mfma_f32_16x16x32_bf16(af[i], bfr[j], acc[i][j], 0, 0, 0);
  }

  #pragma unroll
  for (int i = 0; i < 4; i++) {
    #pragma unroll
    for (int j = 0; j < 4; j++) {
      int col = n0 + wn + j * 16 + lcol;
      float bv = bias[col];
      #pragma unroll
      for (int r = 0; r < 4; r++) {
        int row = m0 + wm + i * 16 + quad * 4 + r;
        float v = acc[i][j][r] + bv;
        if (Cf) Cf[(size_t)row * N + col] = v;
        else {
          unsigned short hv = f2bf(v);
          Cb[(size_t)row * N + col] = hv;
          if (KlTout && n0 == 0)   // latent slab: also write transposed [b][l][t]
            KlTout[((size_t)(row >> 11) * L_ + col) * T_ + (row & 2047)] = hv;
        }
      }
    }
  }
}

// ---------------- fused causal MLA attention (R8, proven 70.5us) ----------------
// Block: 4 waves = 4 heads, 32 q-rows. s-tiles of 64, K tiles double-buffered
// (stage(0); loop { barrier; stage(ts+1 -> other buf); compute(ts) }).
// Swapped QK^T via 32x32x16 MFMA -> S^T: lane holds P for its own q = lane&31.
// P->bf16 PV A-frags in registers: 16 v_cvt_pk_bf16_f32 + 8 v_permlane32_swap
// per tile; per-lane scalar lsum (bit-consistent with MFMA input).
// Kr 4-bit XOR swizzle, Kt 3+1-bit XOR -> <=2-way conflicts.
// Grid 512: n<256 heavy tile (63-qi), n>=256 light (qi) -> pair per CU.
__global__ __launch_bounds__(256, 2) void attn_mla(
    const unsigned short* __restrict__ kq,   // [B*T][NKQ]
    const unsigned short* __restrict__ KlT,  // [B][L][T]
    unsigned short* __restrict__ y) {        // [B*T][NH*L]
  __shared__ __align__(16) unsigned short Kr[2][64 * 128];   // [s][l] swizzled (4-bit XOR)
  __shared__ __align__(16) unsigned short Kt[2][128 * 64];   // [l][s] swizzled (3+1-bit XOR)
  __shared__ __align__(16) float ls[4][32];                  // per-wave 1/lsum exchange

  const int tid  = threadIdx.x;
  const int wave = tid >> 6, lane = tid & 63;
  const int l31 = lane & 31, hf = lane >> 5;
  const int n    = blockIdx.x;
  const int slot = n >> 8, c = n & 255;
  const int hg   = c >> 5, qi = c & 31;
  const int b    = hg >> 2;
  const int h    = (hg & 3) * 4 + wave;
  const int qt32 = slot ? qi : (63 - qi);    // 32-row q-tile index
  const size_t rowbase = (size_t)b * T_;
  const int q0 = qt32 * 32;

  // Q as B-frags for swapped QK^T (n = q = lane&31, k = kc*16 + hf*8 + j)
  short8 qf[8];
  {
    const unsigned short* qp =
        kq + (rowbase + q0 + l31) * NKQ + L_ + h * L_ + hf * 8;
    #pragma unroll
    for (int kc = 0; kc < 8; kc++)
      qf[kc] = *(const short8*)(qp + kc * 16);
  }

  f32x16 acco[4];   // O[32q][128l]: 4 n-blocks of 32; rows = reg-form, col = l31
  #pragma unroll
  for (int nb = 0; nb < 4; nb++)
    #pragma unroll
    for (int r = 0; r < 16; r++) acco[nb][r] = 0.f;
  float lsum = 0.f;

  const int nt = (qt32 >> 1) + 1;

  // prologue: stage tile 0 into buffer 0 (swizzle computed per sub-load!)
  #pragma unroll
  for (int kk = 0; kk < 4; kk++) {
    int r0 = wave * 16 + kk * 4;
    int rg = r0 + (lane >> 4);
    int cl = ((lane & 15) ^ (rg & 15)) * 8;
    GLD16(kq + (rowbase + rg) * NKQ + cl, &Kr[0][r0 * 128]);
  }
  #pragma unroll
  for (int kk = 0; kk < 4; kk++) {
    int r0 = wave * 32 + kk * 8;
    int rg = r0 + (lane >> 3);
    int cl = ((lane & 7) ^ (rg & 7) ^ (((rg >> 3) & 1) << 2)) * 8;
    GLD16(KlT + ((size_t)b * L_ + rg) * T_ + cl, &Kt[0][r0 * 64]);
  }

  for (int ts = 0; ts < nt; ts++) {
    const int cur = ts & 1;
    __syncthreads();  // drains stage(ts) [issued one full phase ago] + guards buf reuse

    if (ts + 1 < nt) {  // prefetch next tile into the other buffer
      const int s1 = (ts + 1) * 64;
      #pragma unroll
      for (int kk = 0; kk < 4; kk++) {
        int r0 = wave * 16 + kk * 4;
        int rg = r0 + (lane >> 4);
        int cl = ((lane & 15) ^ (rg & 15)) * 8;
        GLD16(kq + (rowbase + s1 + rg) * NKQ + cl, &Kr[cur ^ 1][r0 * 128]);
      }
      #pragma unroll
      for (int kk = 0; kk < 4; kk++) {
        int r0 = wave * 32 + kk * 8;
        int rg = r0 + (lane >> 3);
        int cl = ((lane & 7) ^ (rg & 7) ^ (((rg >> 3) & 1) << 2)) * 8;
        GLD16(KlT + ((size_t)b * L_ + rg) * T_ + s1 + cl, &Kt[cur ^ 1][r0 * 64]);
      }
    }

    const unsigned short* Krc = &Kr[cur][0];
    const unsigned short* Ktc = &Kt[cur][0];

    // S^T(64s x 32q) = K @ Q^T : A = K from Kr (m=s), B = Q regs (n=q)
    f32x16 accs[2];
    #pragma unroll
    for (int sb = 0; sb < 2; sb++)
      #pragma unroll
      for (int r = 0; r < 16; r++) accs[sb][r] = 0.f;
    __builtin_amdgcn_s_setprio(1);
    #pragma unroll
    for (int kc = 0; kc < 8; kc++)
      #pragma unroll
      for (int sb = 0; sb < 2; sb++) {
        short8 kf = *(const short8*)&Krc[(sb * 32 + l31) * 128 +
                                          (((2 * kc + hf) ^ (l31 & 15)) * 8)];
        accs[sb] = __builtin_amdgcn_mfma_f32_32x32x16_bf16(kf, qf[kc], accs[sb], 0, 0, 0);
      }
    __builtin_amdgcn_s_setprio(0);

    // mask + p = 2^s (log2e pre-folded into W_d)
    const bool diag = (ts == nt - 1);
    const int qg = (qt32 & 1) * 32 + l31;
    #pragma unroll
    for (int sb = 0; sb < 2; sb++)
      #pragma unroll
      for (int r = 0; r < 16; r++) {
        float v = accs[sb][r];
        int s64 = sb * 32 + (r & 3) + 8 * (r >> 2) + 4 * hf;
        if (diag && s64 > qg) v = -1e30f;
        accs[sb][r] = __builtin_amdgcn_exp2f(v);
      }

    // PV: per kc (s-chunk of 16): build A-frag in regs (cvt_pk + permlane32_swap),
    // then 4 V-frags from Kt and 4 MFMAs. No LDS for P.
    #pragma unroll
    for (int kc = 0; kc < 4; kc++) {
      const int sb = kc >> 1;
      const int t0 = (kc & 1) * 2;          // packs t0 (regs 4t0..) and t0+1
      unsigned w00, w01, w10, w11;
      asm("v_cvt_pk_bf16_f32 %0, %1, %2" : "=v"(w00)
          : "v"(accs[sb][4 * t0 + 0]), "v"(accs[sb][4 * t0 + 1]));
      asm("v_cvt_pk_bf16_f32 %0, %1, %2" : "=v"(w01)
          : "v"(accs[sb][4 * t0 + 2]), "v"(accs[sb][4 * t0 + 3]));
      asm("v_cvt_pk_bf16_f32 %0, %1, %2" : "=v"(w10)
          : "v"(accs[sb][4 * t0 + 4]), "v"(accs[sb][4 * t0 + 5]));
      asm("v_cvt_pk_bf16_f32 %0, %1, %2" : "=v"(w11)
          : "v"(accs[sb][4 * t0 + 6]), "v"(accs[sb][4 * t0 + 7]));
      // VDST.hi <-> VSRC.lo: w00' = {half0 pack[t0]}, w10' = {half1 pack[t]}
      asm volatile("v_permlane32_swap_b32 %0, %1" : "+v"(w00), "+v"(w10));
      asm volatile("v_permlane32_swap_b32 %0, %1" : "+v"(w01), "+v"(w11));
      union { short8 s; unsigned u[4]; } F;
      F.u[0] = w00; F.u[1] = w01; F.u[2] = w10; F.u[3] = w11;
      // lsum from the exact bf16 values fed to the MFMA (own q = l31)
      #pragma unroll
      for (int w = 0; w < 4; w++) {
        lsum += __uint_as_float(F.u[w] << 16);
        lsum += __uint_as_float(F.u[w] & 0xffff0000u);
      }
      __builtin_amdgcn_s_setprio(1);
      #pragma unroll
      for (int nb = 0; nb < 4; nb++) {
        int rowv = nb * 32 + l31;
        short8 vf = *(const short8*)&Ktc[rowv * 64 +
            (((2 * kc + hf) ^ (rowv & 7) ^ (((rowv >> 3) & 1) << 2)) * 8)];
        acco[nb] = __builtin_amdgcn_mfma_f32_32x32x16_bf16(F.s, vf, acco[nb], 0, 0, 0);
      }
      __builtin_amdgcn_s_setprio(0);
    }
  }

  // lsum: merge halves (own half covered s = {16kc + 8*hf + j}), invert, exchange
  lsum += __shfl_xor(lsum, 32, 64);
  if (lane < 32) ls[wave][l31] = 1.f / lsum;
  __syncthreads();
  f32x4 rv[4];
  #pragma unroll
  for (int t = 0; t < 4; t++)
    rv[t] = *(const f32x4*)&ls[wave][8 * t + 4 * hf];

  // write y: q = q0 + (r&3)+8*(r>>2)+4*hf (rows), l = nb*32 + l31 (cols)
  #pragma unroll
  for (int nb = 0; nb < 4; nb++)
    #pragma unroll
    for (int r = 0; r < 16; r++) {
      int q = q0 + (r & 3) + 8 * (r >> 2) + 4 * hf;
      int l = nb * 32 + l31;
      y[(rowbase + q) * (NH_ * L_) + h * L_ + l] =
          f2bf(acco[nb][r] * rv[r >> 2][r & 3]);
    }
}

extern "C" void kernel_launch(void* const* d_in, const int* in_sizes, int n_in,
                              void* d_out, int out_size, void* d_ws, size_t ws_size,
                              hipStream_t stream) {
  const float* x      = (const float*)d_in[0];
  const float* W_lat  = (const float*)d_in[1];
  const float* b_lat  = (const float*)d_in[2];
  const float* W_d    = (const float*)d_in[3];
  const float* b_d    = (const float*)d_in[4];
  const float* W_proj = (const float*)d_in[5];
  const float* b_proj = (const float*)d_in[6];
  float* out = (float*)d_out;

  // workspace layout (bf16 buffers, 16B aligned)
  unsigned short* x_bf   = (unsigned short*)d_ws;                  // [4096][2048]
  unsigned short* BtCat  = x_bf   + (size_t)MTOK * C_;             // [2176][2048]
  unsigned short* WprojT = BtCat  + (size_t)NKQ * C_;              // [2048][2048]
  unsigned short* kqbuf  = WprojT + (size_t)C_ * (NH_ * L_);       // [4096][2176]
  unsigned short* ybuf   = kqbuf  + (size_t)MTOK * NKQ;            // [4096][2048]
  unsigned short* KlT    = ybuf   + (size_t)MTOK * (NH_ * L_);     // [2][128][2048]
  float*          biascat = (float*)(KlT + (size_t)B_ * L_ * T_);  // [2176]

  // 1. merged prep: x->bf16, weight transposes (scale folded), bias concat
  prep_all<<<16649, 256, 0, stream>>>(x, W_lat, W_d, W_proj, b_lat, b_d,
                                      x_bf, BtCat, WprojT, biascat);
  // 2. kq = x @ [W_lat | scale*log2e*W_d] + bias (bf16 out) + fused latent transpose
  gemm_bt_bias<<<dim3(MTOK / 128, NKQ / 128), 256, 0, stream>>>(
      x_bf, BtCat, biascat, kqbuf, nullptr, KlT, MTOK, NKQ, C_);
  // 3. causal MLA attention (512 balanced blocks, R8 staged version)
  attn_mla<<<512, 256, 0, stream>>>(kqbuf, KlT, ybuf);
  // 4. out = y @ W_proj + b_proj (fp32 out)
  gemm_bt_bias<<<dim3(MTOK / 128, C_ / 128), 256, 0, stream>>>(
      ybuf, WprojT, b_proj, nullptr, out, nullptr, MTOK, C_, C_);
}